// Round 6
// baseline (257.022 us; speedup 1.0000x reference)
//
#include <hip/hip_runtime.h>
#include <math.h>

#define Bz 32
#define Sz 4096
#define Hz 32
#define Gz 2
#define Dz 128
#define HIDz 4096
#define QKVz 4608
#define NCHc 32   // combine chunks per (b,g); chunk = 4 contiguous variable-length units

static __device__ __forceinline__ void fma4(float4& a, float s, const float4& v) {
  a.x = fmaf(s, v.x, a.x);
  a.y = fmaf(s, v.y, a.y);
  a.z = fmaf(s, v.z, a.z);
  a.w = fmaf(s, v.w, a.w);
}

// ---------------- split-K GEMM partial: part[kt][b][j] = sum_{k in chunk} X[b][k]*W[k][j]
__global__ __launch_bounds__(256) void gemm_partial(
    const float* __restrict__ X, const float* __restrict__ W,
    float* __restrict__ part, int K, int N, int KH) {
  extern __shared__ float hl[];  // [32][KH+4]
  const int stride = KH + 4;
  const int t = threadIdx.x;
  const int k0 = blockIdx.y * KH;
  const int cols4 = KH >> 2;
  const int total4 = Bz * cols4;
  for (int fi = t; fi < total4; fi += 256) {
    const int row = fi / cols4;
    const int c4 = fi - row * cols4;
    const float4 v = *(const float4*)&X[(size_t)row * K + k0 + c4 * 4];
    *(float4*)&hl[row * stride + c4 * 4] = v;
  }
  __syncthreads();
  const int jl = t & 31;
  const int b0 = (t >> 5) * 4;
  const int j = blockIdx.x * 128 + jl * 4;
  float4 acc[4];
  #pragma unroll
  for (int i = 0; i < 4; i++) acc[i] = make_float4(0.f, 0.f, 0.f, 0.f);
  #pragma unroll 4
  for (int kk = 0; kk < KH; kk += 4) {
    const float4 w0 = *(const float4*)&W[(size_t)(k0 + kk + 0) * N + j];
    const float4 w1 = *(const float4*)&W[(size_t)(k0 + kk + 1) * N + j];
    const float4 w2 = *(const float4*)&W[(size_t)(k0 + kk + 2) * N + j];
    const float4 w3 = *(const float4*)&W[(size_t)(k0 + kk + 3) * N + j];
    #pragma unroll
    for (int bi = 0; bi < 4; bi++) {
      const float4 hb = *(const float4*)&hl[(b0 + bi) * stride + kk];
      fma4(acc[bi], hb.x, w0);
      fma4(acc[bi], hb.y, w1);
      fma4(acc[bi], hb.z, w2);
      fma4(acc[bi], hb.w, w3);
    }
  }
  #pragma unroll
  for (int bi = 0; bi < 4; bi++) {
    *(float4*)&part[((size_t)blockIdx.y * Bz + b0 + bi) * N + j] = acc[bi];
  }
}

// ---------------- reduce QKV partials + bias, RoPE, emit qrot (pre-scaled), krot, vnew
__global__ __launch_bounds__(256) void qkv_finish(
    const float* __restrict__ part, const float* __restrict__ bias,
    const int* __restrict__ positions, int KT,
    float* __restrict__ qrot, float* __restrict__ krot, float* __restrict__ vnew) {
  const int t = threadIdx.x;
  const int b = blockIdx.x;
  const int head = blockIdx.y * 4 + (t >> 6);
  const int tp = t & 63;
  const int j0 = head * Dz + tp * 2;
  float s0 = bias[j0];
  float s1 = bias[j0 + 1];
  for (int kt = 0; kt < KT; kt++) {
    const float2 p = *(const float2*)&part[((size_t)kt * Bz + b) * QKVz + j0];
    s0 += p.x;
    s1 += p.y;
  }
  float o0 = s0, o1 = s1;
  if (head < Hz + Gz && tp < 32) {
    const float invf = exp2f(-(float)tp * (13.287712379549449f / 32.0f));
    const float a = (float)positions[b] * invf;
    float sn, cs;
    sincosf(a, &sn, &cs);
    o0 = s0 * cs - s1 * sn;
    o1 = s1 * cs + s0 * sn;
  }
  if (head < Hz) {
    const float sc = 0.08838834764831845f;
    float2 o = make_float2(o0 * sc, o1 * sc);
    *(float2*)&qrot[((size_t)b * Hz + head) * Dz + tp * 2] = o;
  } else if (head < Hz + Gz) {
    float2 o = make_float2(o0, o1);
    *(float2*)&krot[((size_t)b * Gz + (head - Hz)) * Dz + tp * 2] = o;
  } else {
    float2 o = make_float2(s0, s1);
    *(float2*)&vnew[((size_t)b * Gz + (head - Hz - Gz)) * Dz + tp * 2] = o;
  }
}

// ---------------- flash unit (balanced contiguous spans): unit u = bx*4+w owns rows
// [u*(pos+1)/128, (u+1)*(pos+1)/128) -- contiguous, <=32 rows, equal work all blocks.
// Lane (hq,sq): QK = 4 heads x 2 row-slots (lo+sq, lo+16+sq); PV = 4 heads x 8 d.
// grid (32, G, B), block 256, 18.2 KB LDS, __launch_bounds__(256,8).
__global__ __launch_bounds__(256, 8) void attn_unit(
    const float* __restrict__ qrot, const float* __restrict__ kcache,
    const float* __restrict__ vcache, const float* __restrict__ krot,
    const float* __restrict__ vnew, const int* __restrict__ positions,
    float* __restrict__ mbuf, float* __restrict__ lbuf, float* __restrict__ pacc) {
  __shared__ float smem[4544];
  // qs = smem[0..2112) (16x132), aliased as Aw in combine; plw[w]=smem[2112+w*576) (16x36);
  // ml = smem[4416..4544)
  float* qs = smem;
  const int g = blockIdx.y, b = blockIdx.z;
  const int pos = positions[b];
  const int t = threadIdx.x;
  for (int i = t; i < 16 * 32; i += 256) {
    const int row = i >> 5, c4 = i & 31;
    *(float4*)&qs[row * 132 + c4 * 4] =
        *(const float4*)&qrot[((size_t)b * Hz + g * 16 + row) * Dz + (c4)*4];
  }
  __syncthreads();

  const int w = t >> 6;
  const int lane = t & 63;
  const int hq = lane >> 4;
  const int sq = lane & 15;
  float* plw = smem + 2112 + w * 576;
  const int u = blockIdx.x * 4 + w;          // unit in [0,128)
  const int lt = pos + 1;
  const int lo = (u * lt) >> 7;
  const int hi_b = ((u + 1) * lt) >> 7;
  const int nr = hi_b - lo;                  // 0..32 valid rows, contiguous [lo, hi_b)

  float m_run[4], l_run[4];
  float4 A[4][2];
  #pragma unroll
  for (int i = 0; i < 4; i++) {
    m_run[i] = -1e30f;
    l_run[i] = 0.f;
    A[i][0] = make_float4(0.f, 0.f, 0.f, 0.f);
    A[i][1] = make_float4(0.f, 0.f, 0.f, 0.f);
  }

  if (nr > 0) {
    const bool two = nr > 16;
    const float* krow_new = &krot[((size_t)b * Gz + g) * Dz];
    const float* vrow_new = &vnew[((size_t)b * Gz + g) * Dz];
    const size_t kvb = ((size_t)b * Sz) * (Gz * Dz) + (size_t)g * Dz;

    const int sgA = lo + sq;
    const int sgB = lo + 16 + sq;
    // clamp invalid/replaced rows to the fresh K row (L1-resident broadcast; masked later)
    const float* kpA = (sgA >= hi_b || sgA == pos) ? krow_new
                        : &kcache[kvb + (size_t)sgA * (Gz * Dz)];
    const float* kpB = (sgB >= hi_b || sgB == pos) ? krow_new
                        : &kcache[kvb + (size_t)sgB * (Gz * Dz)];
    float acc[4][2];
    #pragma unroll
    for (int i = 0; i < 4; i++) { acc[i][0] = 0.f; acc[i][1] = 0.f; }

#define QK1(buf, c)                                                       \
    { _Pragma("unroll") for (int j = 0; j < 4; ++j) {                     \
        _Pragma("unroll") for (int i = 0; i < 4; ++i) {                   \
          const float4 q = *(const float4*)&qs[(hq * 4 + i) * 132 + ((c) * 4 + j) * 4]; \
          acc[i][0] = fmaf(q.x, buf[j].x, fmaf(q.y, buf[j].y, fmaf(q.z, buf[j].z, fmaf(q.w, buf[j].w, acc[i][0])))); } } }
#define QK2(buf, c)                                                       \
    { _Pragma("unroll") for (int j = 0; j < 4; ++j) {                     \
        _Pragma("unroll") for (int i = 0; i < 4; ++i) {                   \
          const float4 q = *(const float4*)&qs[(hq * 4 + i) * 132 + ((c) * 4 + j) * 4]; \
          acc[i][0] = fmaf(q.x, buf[j][0].x, fmaf(q.y, buf[j][0].y, fmaf(q.z, buf[j][0].z, fmaf(q.w, buf[j][0].w, acc[i][0])))); \
          acc[i][1] = fmaf(q.x, buf[j][1].x, fmaf(q.y, buf[j][1].y, fmaf(q.z, buf[j][1].z, fmaf(q.w, buf[j][1].w, acc[i][1])))); } } }
    if (two) {
      float4 ka[4][2], kb[4][2];
#define BK2(buf, c)                                                       \
      { _Pragma("unroll") for (int j = 0; j < 4; ++j) {                   \
          buf[j][0] = *(const float4*)&kpA[((c) * 4 + j) * 4];            \
          buf[j][1] = *(const float4*)&kpB[((c) * 4 + j) * 4]; } }
      BK2(ka, 0); BK2(kb, 1);
      QK2(ka, 0); BK2(ka, 2);
      QK2(kb, 1); BK2(kb, 3);
      QK2(ka, 2); BK2(ka, 4);
      QK2(kb, 3); BK2(kb, 5);
      QK2(ka, 4); BK2(ka, 6);
      QK2(kb, 5); BK2(kb, 7);
      QK2(ka, 6); QK2(kb, 7);
#undef BK2
      if (16 + sq >= nr) {
        #pragma unroll
        for (int i = 0; i < 4; ++i) acc[i][1] = -1e30f;
      }
    } else {
      float4 ka[4], kb[4];
#define BK1(buf, c)                                                       \
      { _Pragma("unroll") for (int j = 0; j < 4; ++j)                     \
          buf[j] = *(const float4*)&kpA[((c) * 4 + j) * 4]; }
      BK1(ka, 0); BK1(kb, 1);
      QK1(ka, 0); BK1(ka, 2);
      QK1(kb, 1); BK1(kb, 3);
      QK1(ka, 2); BK1(ka, 4);
      QK1(kb, 3); BK1(kb, 5);
      QK1(ka, 4); BK1(ka, 6);
      QK1(kb, 5); BK1(kb, 7);
      QK1(ka, 6); QK1(kb, 7);
#undef BK1
      if (sq >= nr) {
        #pragma unroll
        for (int i = 0; i < 4; ++i) acc[i][0] = -1e30f;
      }
      #pragma unroll
      for (int i = 0; i < 4; ++i) acc[i][1] = -1e30f;
    }
#undef QK1
#undef QK2
    // ---- softmax (within 16-lane segment); plw[h][s], s = row - lo
    #pragma unroll
    for (int i = 0; i < 4; ++i) {
      float tm = fmaxf(acc[i][0], acc[i][1]);
      tm = fmaxf(tm, __shfl_xor(tm, 1, 16));
      tm = fmaxf(tm, __shfl_xor(tm, 2, 16));
      tm = fmaxf(tm, __shfl_xor(tm, 4, 16));
      tm = fmaxf(tm, __shfl_xor(tm, 8, 16));
      m_run[i] = tm;
      const float p0 = __expf(acc[i][0] - tm);
      const float p1 = __expf(acc[i][1] - tm);
      float ts = p0 + p1;
      ts += __shfl_xor(ts, 1, 16);
      ts += __shfl_xor(ts, 2, 16);
      ts += __shfl_xor(ts, 4, 16);
      ts += __shfl_xor(ts, 8, 16);
      l_run[i] = ts;
      plw[(hq * 4 + i) * 36 + sq] = p0;
      if (two) plw[(hq * 4 + i) * 36 + 16 + sq] = p1;
    }
    // ---- PV: lane = 4 heads x 8 d; groups of 4 row-slots, dbuf bursts
    float4 va[4][2], vb[4][2];
#define BV(buf, rg)                                                       \
    { _Pragma("unroll") for (int r = 0; r < 4; ++r) {                     \
        const int sg = lo + (rg) * 4 + r;                                 \
        const float* vp = (sg >= hi_b || sg == pos) ? vrow_new            \
                           : &vcache[kvb + (size_t)sg * (Gz * Dz)];       \
        buf[r][0] = *(const float4*)&vp[sq * 8];                          \
        buf[r][1] = *(const float4*)&vp[sq * 8 + 4]; } }
#define PVC(buf, rg)                                                      \
    { float4 pf[4];                                                       \
      _Pragma("unroll") for (int i = 0; i < 4; ++i)                       \
        pf[i] = *(const float4*)&plw[(hq * 4 + i) * 36 + (rg) * 4];       \
      _Pragma("unroll") for (int r = 0; r < 4; ++r) {                     \
        _Pragma("unroll") for (int i = 0; i < 4; ++i) {                   \
          const float pr = ((const float*)&pf[i])[r];                     \
          fma4(A[i][0], pr, buf[r][0]);                                   \
          fma4(A[i][1], pr, buf[r][1]); } } }
    BV(va, 0); BV(vb, 1);
    PVC(va, 0); BV(va, 2);
    PVC(vb, 1); BV(vb, 3);
    PVC(va, 2);
    if (two) {
      BV(va, 4); PVC(vb, 3);
      BV(vb, 5); PVC(va, 4);
      BV(va, 6); PVC(vb, 5);
      BV(vb, 7); PVC(va, 6);
      PVC(vb, 7);
    } else {
      PVC(vb, 3);
    }
#undef BV
#undef PVC
  }

  // ---- in-block combine: serial accumulate through one 16x132 buffer (aliases qs)
  __syncthreads();
  float* ml = smem + 4416;
  if (sq == 0) {
    #pragma unroll
    for (int i = 0; i < 4; ++i) {
      ml[w * 32 + hq * 4 + i] = m_run[i];
      ml[w * 32 + 16 + hq * 4 + i] = l_run[i];
    }
  }
  __syncthreads();
  float ew[4];
  #pragma unroll
  for (int i = 0; i < 4; ++i) {
    const int h = hq * 4 + i;
    const float ms = fmaxf(fmaxf(ml[h], ml[32 + h]), fmaxf(ml[64 + h], ml[96 + h]));
    ew[i] = __expf(m_run[i] - ms);
  }
  float* Aw = smem;  // 16 x 132
  for (int step = 0; step < 4; ++step) {
    if (w == step) {
      #pragma unroll
      for (int i = 0; i < 4; ++i) {
        const int h = hq * 4 + i;
        if (step == 0) {
          float4 x0 = make_float4(ew[i] * A[i][0].x, ew[i] * A[i][0].y,
                                  ew[i] * A[i][0].z, ew[i] * A[i][0].w);
          float4 x1 = make_float4(ew[i] * A[i][1].x, ew[i] * A[i][1].y,
                                  ew[i] * A[i][1].z, ew[i] * A[i][1].w);
          *(float4*)&Aw[h * 132 + sq * 8] = x0;
          *(float4*)&Aw[h * 132 + sq * 8 + 4] = x1;
        } else {
          float4 c0 = *(const float4*)&Aw[h * 132 + sq * 8];
          float4 c1 = *(const float4*)&Aw[h * 132 + sq * 8 + 4];
          fma4(c0, ew[i], A[i][0]);
          fma4(c1, ew[i], A[i][1]);
          *(float4*)&Aw[h * 132 + sq * 8] = c0;
          *(float4*)&Aw[h * 132 + sq * 8 + 4] = c1;
        }
      }
    }
    __syncthreads();
  }
  const size_t cb = (size_t)(b * Gz + g) * NCHc + blockIdx.x;
  for (int o = t; o < 512; o += 256) {
    const int h = o >> 5, d4c = o & 31;
    *(float4*)&pacc[cb * 2048 + (size_t)h * Dz + d4c * 4] =
        *(const float4*)&Aw[h * 132 + d4c * 4];
  }
  if (t < 16) {
    const int h = t;
    const float m0 = ml[h], m1 = ml[32 + h], m2 = ml[64 + h], m3 = ml[96 + h];
    const float ms = fmaxf(fmaxf(m0, m1), fmaxf(m2, m3));
    const float l = __expf(m0 - ms) * ml[16 + h] + __expf(m1 - ms) * ml[48 + h] +
                    __expf(m2 - ms) * ml[80 + h] + __expf(m3 - ms) * ml[112 + h];
    mbuf[cb * 16 + h] = ms;
    lbuf[cb * 16 + h] = l;
  }
}

// ---------------- combine chunk partials -> ctx (B, H*D)
__global__ __launch_bounds__(512) void attn_combine(
    const float* __restrict__ mbuf, const float* __restrict__ lbuf,
    const float* __restrict__ pacc, const int* __restrict__ positions,
    float* __restrict__ ctx) {
  const int bg = blockIdx.x;
  const int b = bg >> 1, g = bg & 1;
  const int t = threadIdx.x;
  const int h = t >> 5, dg = t & 31;
  const size_t mlb = (size_t)bg * NCHc * 16 + h;
  float mstar = -1e30f;
  for (int c = 0; c < NCHc; c++) mstar = fmaxf(mstar, mbuf[mlb + c * 16]);
  float lsum = 0.f;
  float4 A = make_float4(0.f, 0.f, 0.f, 0.f);
  for (int c = 0; c < NCHc; c++) {
    const float wv = __expf(mbuf[mlb + c * 16] - mstar);
    lsum += wv * lbuf[mlb + c * 16];
    const float4 p = *(const float4*)&pacc[((size_t)bg * NCHc + c) * 2048 + (size_t)h * Dz + dg * 4];
    fma4(A, wv, p);
  }
  const float inv = 1.0f / lsum;
  float4 o = make_float4(A.x * inv, A.y * inv, A.z * inv, A.w * inv);
  *(float4*)&ctx[(size_t)b * (Hz * Dz) + (g * 16 + h) * Dz + dg * 4] = o;
}

// ---------------- reduce dense partials -> out
__global__ __launch_bounds__(256) void reduce_out(
    const float* __restrict__ part, float* __restrict__ out, int KT) {
  const int idx = blockIdx.x * 256 + threadIdx.x;
  const int b = idx >> 12;
  const int j = idx & 4095;
  float s = 0.f;
  for (int kt = 0; kt < KT; kt++) s += part[((size_t)kt * Bz + b) * HIDz + j];
  out[idx] = s;
}

extern "C" void kernel_launch(void* const* d_in, const int* in_sizes, int n_in,
                              void* d_out, int out_size, void* d_ws, size_t ws_size,
                              hipStream_t stream) {
  const float* hidden = (const float*)d_in[0];
  const int* positions = (const int*)d_in[1];
  const float* kcache = (const float*)d_in[2];
  const float* vcache = (const float*)d_in[3];
  const float* Wqkv = (const float*)d_in[4];
  const float* bqkv = (const float*)d_in[5];
  const float* Wd = (const float*)d_in[6];
  float* out = (float*)d_out;

  auto need = [](int KT) -> size_t {
    return (size_t)KT * Bz * QKVz
         + (size_t)Bz * Hz * Dz
         + (size_t)Bz * Gz * Dz * 2
         + (size_t)Bz * Gz * NCHc * 16 * 2
         + (size_t)Bz * Gz * NCHc * 2048
         + (size_t)Bz * HIDz;
  };
  int KT = 32;
  if (need(32) * sizeof(float) > ws_size) KT = 16;
  const int KH = HIDz / KT;

  float* w = (float*)d_ws;
  float* p1 = w;    w += (size_t)KT * Bz * QKVz;
  float* qrot = w;  w += (size_t)Bz * Hz * Dz;
  float* krot = w;  w += (size_t)Bz * Gz * Dz;
  float* vnew = w;  w += (size_t)Bz * Gz * Dz;
  float* mbuf = w;  w += (size_t)Bz * Gz * NCHc * 16;
  float* lbuf = w;  w += (size_t)Bz * Gz * NCHc * 16;
  float* pacc = w;  w += (size_t)Bz * Gz * NCHc * 2048;
  float* ctx = w;

  const size_t smem = (size_t)Bz * (KH + 4) * sizeof(float);

  gemm_partial<<<dim3(QKVz / 128, KT), 256, smem, stream>>>(hidden, Wqkv, p1, HIDz, QKVz, KH);
  qkv_finish<<<dim3(Bz, 9), 256, 0, stream>>>(p1, bqkv, positions, KT, qrot, krot, vnew);
  attn_unit<<<dim3(NCHc, Gz, Bz), 256, 0, stream>>>(qrot, kcache, vcache, krot, vnew, positions,
                                                    mbuf, lbuf, pacc);
  attn_combine<<<dim3(Bz * Gz), 512, 0, stream>>>(mbuf, lbuf, pacc, positions, ctx);
  gemm_partial<<<dim3(HIDz / 128, KT), 256, smem, stream>>>(ctx, Wd, p1, Hz * Dz, HIDz, KH);
  reduce_out<<<dim3(Bz * HIDz / 256), 256, 0, stream>>>(p1, out, KT);
}

// Round 8
// 180.111 us; speedup vs baseline: 1.4270x; 1.4270x over previous
//
#include <hip/hip_runtime.h>
#include <math.h>

#define Bz 32
#define Sz 4096
#define Hz 32
#define Gz 2
#define Dz 128
#define HIDz 4096
#define QKVz 4608
#define NCHc 16   // combine chunks per (b,g); chunk = 4 contiguous 64-row-span units

static __device__ __forceinline__ void fma4(float4& a, float s, const float4& v) {
  a.x = fmaf(s, v.x, a.x);
  a.y = fmaf(s, v.y, a.y);
  a.z = fmaf(s, v.z, a.z);
  a.w = fmaf(s, v.w, a.w);
}

// ---------------- split-K GEMM partial: part[kt][b][j] = sum_{k in chunk} X[b][k]*W[k][j]
__global__ __launch_bounds__(256) void gemm_partial(
    const float* __restrict__ X, const float* __restrict__ W,
    float* __restrict__ part, int K, int N, int KH) {
  extern __shared__ float hl[];  // [32][KH+4]
  const int stride = KH + 4;
  const int t = threadIdx.x;
  const int k0 = blockIdx.y * KH;
  const int cols4 = KH >> 2;
  const int total4 = Bz * cols4;
  for (int fi = t; fi < total4; fi += 256) {
    const int row = fi / cols4;
    const int c4 = fi - row * cols4;
    const float4 v = *(const float4*)&X[(size_t)row * K + k0 + c4 * 4];
    *(float4*)&hl[row * stride + c4 * 4] = v;
  }
  __syncthreads();
  const int jl = t & 31;
  const int b0 = (t >> 5) * 4;
  const int j = blockIdx.x * 128 + jl * 4;
  float4 acc[4];
  #pragma unroll
  for (int i = 0; i < 4; i++) acc[i] = make_float4(0.f, 0.f, 0.f, 0.f);
  #pragma unroll 4
  for (int kk = 0; kk < KH; kk += 4) {
    const float4 w0 = *(const float4*)&W[(size_t)(k0 + kk + 0) * N + j];
    const float4 w1 = *(const float4*)&W[(size_t)(k0 + kk + 1) * N + j];
    const float4 w2 = *(const float4*)&W[(size_t)(k0 + kk + 2) * N + j];
    const float4 w3 = *(const float4*)&W[(size_t)(k0 + kk + 3) * N + j];
    #pragma unroll
    for (int bi = 0; bi < 4; bi++) {
      const float4 hb = *(const float4*)&hl[(b0 + bi) * stride + kk];
      fma4(acc[bi], hb.x, w0);
      fma4(acc[bi], hb.y, w1);
      fma4(acc[bi], hb.z, w2);
      fma4(acc[bi], hb.w, w3);
    }
  }
  #pragma unroll
  for (int bi = 0; bi < 4; bi++) {
    *(float4*)&part[((size_t)blockIdx.y * Bz + b0 + bi) * N + j] = acc[bi];
  }
}

// ---------------- reduce QKV partials + bias, RoPE, emit qrot (pre-scaled), krot, vnew
__global__ __launch_bounds__(256) void qkv_finish(
    const float* __restrict__ part, const float* __restrict__ bias,
    const int* __restrict__ positions, int KT,
    float* __restrict__ qrot, float* __restrict__ krot, float* __restrict__ vnew) {
  const int t = threadIdx.x;
  const int b = blockIdx.x;
  const int head = blockIdx.y * 4 + (t >> 6);
  const int tp = t & 63;
  const int j0 = head * Dz + tp * 2;
  float s0 = bias[j0];
  float s1 = bias[j0 + 1];
  for (int kt = 0; kt < KT; kt++) {
    const float2 p = *(const float2*)&part[((size_t)kt * Bz + b) * QKVz + j0];
    s0 += p.x;
    s1 += p.y;
  }
  float o0 = s0, o1 = s1;
  if (head < Hz + Gz && tp < 32) {
    const float invf = exp2f(-(float)tp * (13.287712379549449f / 32.0f));
    const float a = (float)positions[b] * invf;
    float sn, cs;
    sincosf(a, &sn, &cs);
    o0 = s0 * cs - s1 * sn;
    o1 = s1 * cs + s0 * sn;
  }
  if (head < Hz) {
    const float sc = 0.08838834764831845f;
    float2 o = make_float2(o0 * sc, o1 * sc);
    *(float2*)&qrot[((size_t)b * Hz + head) * Dz + tp * 2] = o;
  } else if (head < Hz + Gz) {
    float2 o = make_float2(o0, o1);
    *(float2*)&krot[((size_t)b * Gz + (head - Hz)) * Dz + tp * 2] = o;
  } else {
    float2 o = make_float2(s0, s1);
    *(float2*)&vnew[((size_t)b * Gz + (head - Hz - Gz)) * Dz + tp * 2] = o;
  }
}

// QK inner: NBLK active 16-row blocks; lane computes acc[head i][block rb] for row lo+rb*16+sq.
// One Q LDS broadcast (b128) feeds 4 heads x NBLK rows (16*NBLK FMA per read).
// Narrow 2-deep dbuf: ka/kb hold one float4 per block (32 VGPR total).
template <int NBLK>
static __device__ __forceinline__ void qk_phase(
    const float* __restrict__ qs, int hq,
    const float* kp0, const float* kp1, const float* kp2, const float* kp3,
    float (&acc)[4][4]) {
  const float* kp[4] = {kp0, kp1, kp2, kp3};
  float4 ka[NBLK], kb[NBLK];
#define LD(buf, c)                                                        \
  { _Pragma("unroll") for (int rb = 0; rb < NBLK; ++rb)                   \
      buf[rb] = *(const float4*)&kp[rb][(c) * 4]; }
#define CP(buf, c)                                                        \
  { _Pragma("unroll") for (int i = 0; i < 4; ++i) {                       \
      const float4 q = *(const float4*)&qs[(hq * 4 + i) * 132 + (c) * 4]; \
      _Pragma("unroll") for (int rb = 0; rb < NBLK; ++rb) {               \
        acc[i][rb] = fmaf(q.x, buf[rb].x, fmaf(q.y, buf[rb].y,            \
                     fmaf(q.z, buf[rb].z, fmaf(q.w, buf[rb].w, acc[i][rb])))); } } }
  LD(ka, 0);
  LD(kb, 1);
  #pragma unroll
  for (int c = 0; c < 32; c += 2) {
    CP(ka, c);
    if (c + 2 < 32) LD(ka, c + 2);
    CP(kb, c + 1);
    if (c + 3 < 32) LD(kb, c + 3);
  }
#undef LD
#undef CP
}

// ---------------- flash unit: wave-unit u = bx*4+w owns contiguous balanced span
// [u*(pos+1)/64, (u+1)*(pos+1)/64) (<=64 rows). Lane (hq,sq): QK = 4 heads x 4 row-blocks
// (rows lo+rb*16+sq); PV = 4 heads x 8 d over 2-row groups. grid (16, G, B), block 256.
__global__ __launch_bounds__(256, 4) void attn_unit(
    const float* __restrict__ qrot, const float* __restrict__ kcache,
    const float* __restrict__ vcache, const float* __restrict__ krot,
    const float* __restrict__ vnew, const int* __restrict__ positions,
    float* __restrict__ mbuf, float* __restrict__ lbuf, float* __restrict__ pacc) {
  __shared__ float smem[6592];
  // qs = smem[0..2112) (16x132), aliased as Aw in combine;
  // plw[w] = smem[2112 + w*1088) (16x68); ml = smem[6464..6592)
  float* qs = smem;
  const int g = blockIdx.y, b = blockIdx.z;
  const int pos = positions[b];
  const int t = threadIdx.x;
  for (int i = t; i < 16 * 32; i += 256) {
    const int row = i >> 5, c4 = i & 31;
    *(float4*)&qs[row * 132 + c4 * 4] =
        *(const float4*)&qrot[((size_t)b * Hz + g * 16 + row) * Dz + c4 * 4];
  }
  __syncthreads();

  const int w = t >> 6;
  const int lane = t & 63;
  const int hq = lane >> 4;
  const int sq = lane & 15;
  float* plw = smem + 2112 + w * 1088;
  const int u = blockIdx.x * 4 + w;          // unit in [0,64)
  const int lt = pos + 1;
  const int lo = (u * lt) >> 6;
  const int hi_b = ((u + 1) * lt) >> 6;
  const int nr = hi_b - lo;                  // 0..64 contiguous valid rows

  float m_run[4], l_run[4];
  float4 A[4][2];
  #pragma unroll
  for (int i = 0; i < 4; i++) {
    m_run[i] = -1e30f;
    l_run[i] = 0.f;
    A[i][0] = make_float4(0.f, 0.f, 0.f, 0.f);
    A[i][1] = make_float4(0.f, 0.f, 0.f, 0.f);
  }

  if (nr > 0) {
    const int nblk = (nr + 15) >> 4;         // active 16-row blocks (1..4), wave-uniform
    const float* krow_new = &krot[((size_t)b * Gz + g) * Dz];
    const float* vrow_new = &vnew[((size_t)b * Gz + g) * Dz];
    const size_t kvb = ((size_t)b * Sz) * (Gz * Dz) + (size_t)g * Dz;

    const float* kp[4];
    #pragma unroll
    for (int rb = 0; rb < 4; ++rb) {
      const int sg = lo + rb * 16 + sq;
      kp[rb] = (sg >= hi_b || sg == pos) ? krow_new : &kcache[kvb + (size_t)sg * (Gz * Dz)];
    }
    float acc[4][4];
    #pragma unroll
    for (int i = 0; i < 4; i++)
      #pragma unroll
      for (int rb = 0; rb < 4; rb++) acc[i][rb] = 0.f;

    switch (nblk) {
      case 1: qk_phase<1>(qs, hq, kp[0], kp[1], kp[2], kp[3], acc); break;
      case 2: qk_phase<2>(qs, hq, kp[0], kp[1], kp[2], kp[3], acc); break;
      case 3: qk_phase<3>(qs, hq, kp[0], kp[1], kp[2], kp[3], acc); break;
      default: qk_phase<4>(qs, hq, kp[0], kp[1], kp[2], kp[3], acc); break;
    }
    // mask rows beyond span (incl. untouched rb >= nblk)
    #pragma unroll
    for (int rb = 0; rb < 4; ++rb) {
      if (rb * 16 + sq >= nr) {
        #pragma unroll
        for (int i = 0; i < 4; ++i) acc[i][rb] = -1e30f;
      }
    }
    // ---- softmax (within 16-lane segment); plw[h][s], s = row - lo
    #pragma unroll
    for (int i = 0; i < 4; ++i) {
      float tm = fmaxf(fmaxf(acc[i][0], acc[i][1]), fmaxf(acc[i][2], acc[i][3]));
      tm = fmaxf(tm, __shfl_xor(tm, 1, 16));
      tm = fmaxf(tm, __shfl_xor(tm, 2, 16));
      tm = fmaxf(tm, __shfl_xor(tm, 4, 16));
      tm = fmaxf(tm, __shfl_xor(tm, 8, 16));
      m_run[i] = tm;
      const float p0 = __expf(acc[i][0] - tm);
      const float p1 = __expf(acc[i][1] - tm);
      const float p2 = __expf(acc[i][2] - tm);
      const float p3 = __expf(acc[i][3] - tm);
      float ts = (p0 + p1) + (p2 + p3);
      ts += __shfl_xor(ts, 1, 16);
      ts += __shfl_xor(ts, 2, 16);
      ts += __shfl_xor(ts, 4, 16);
      ts += __shfl_xor(ts, 8, 16);
      l_run[i] = ts;
      const int hb = (hq * 4 + i) * 68;
      plw[hb + sq] = p0;
      plw[hb + 16 + sq] = p1;
      plw[hb + 32 + sq] = p2;
      plw[hb + 48 + sq] = p3;
    }
    // ---- PV: lane = 4 heads x 8 d; 2-row groups, 2-deep dbuf; consume BEFORE prefetch
    const int ng2 = (nr + 1) >> 1;           // 1..32, wave-uniform
    float4 va[2][2], vb[2][2];
#define BV(buf, g2)                                                       \
    { _Pragma("unroll") for (int r = 0; r < 2; ++r) {                     \
        const int sg = lo + (g2) * 2 + r;                                 \
        const float* vp = (sg >= hi_b || sg == pos) ? vrow_new            \
                           : &vcache[kvb + (size_t)sg * (Gz * Dz)];       \
        buf[r][0] = *(const float4*)&vp[sq * 8];                          \
        buf[r][1] = *(const float4*)&vp[sq * 8 + 4]; } }
#define PVC(buf, g2)                                                      \
    { _Pragma("unroll") for (int i = 0; i < 4; ++i) {                     \
        const float2 pf = *(const float2*)&plw[(hq * 4 + i) * 68 + (g2) * 2]; \
        fma4(A[i][0], pf.x, buf[0][0]);                                   \
        fma4(A[i][1], pf.x, buf[0][1]);                                   \
        fma4(A[i][0], pf.y, buf[1][0]);                                   \
        fma4(A[i][1], pf.y, buf[1][1]); } }
    BV(va, 0);
    if (ng2 > 1) BV(vb, 1);
    for (int g2 = 0; g2 < ng2; g2 += 2) {
      PVC(va, g2);
      if (g2 + 2 < ng2) BV(va, g2 + 2);
      if (g2 + 1 < ng2) {
        PVC(vb, g2 + 1);
        if (g2 + 3 < ng2) BV(vb, g2 + 3);
      }
    }
#undef BV
#undef PVC
  }

  // ---- in-block combine: serial accumulate through Aw (aliases qs)
  __syncthreads();
  float* ml = smem + 6464;
  if (sq == 0) {
    #pragma unroll
    for (int i = 0; i < 4; ++i) {
      ml[w * 32 + hq * 4 + i] = m_run[i];
      ml[w * 32 + 16 + hq * 4 + i] = l_run[i];
    }
  }
  __syncthreads();
  float ew[4];
  #pragma unroll
  for (int i = 0; i < 4; ++i) {
    const int h = hq * 4 + i;
    const float ms = fmaxf(fmaxf(ml[h], ml[32 + h]), fmaxf(ml[64 + h], ml[96 + h]));
    ew[i] = __expf(m_run[i] - ms);
  }
  float* Aw = smem;  // 16 x 132
  for (int step = 0; step < 4; ++step) {
    if (w == step) {
      #pragma unroll
      for (int i = 0; i < 4; ++i) {
        const int h = hq * 4 + i;
        if (step == 0) {
          float4 x0 = make_float4(ew[i] * A[i][0].x, ew[i] * A[i][0].y,
                                  ew[i] * A[i][0].z, ew[i] * A[i][0].w);
          float4 x1 = make_float4(ew[i] * A[i][1].x, ew[i] * A[i][1].y,
                                  ew[i] * A[i][1].z, ew[i] * A[i][1].w);
          *(float4*)&Aw[h * 132 + sq * 8] = x0;
          *(float4*)&Aw[h * 132 + sq * 8 + 4] = x1;
        } else {
          float4 c0 = *(const float4*)&Aw[h * 132 + sq * 8];
          float4 c1 = *(const float4*)&Aw[h * 132 + sq * 8 + 4];
          fma4(c0, ew[i], A[i][0]);
          fma4(c1, ew[i], A[i][1]);
          *(float4*)&Aw[h * 132 + sq * 8] = c0;
          *(float4*)&Aw[h * 132 + sq * 8 + 4] = c1;
        }
      }
    }
    __syncthreads();
  }
  const size_t cb = (size_t)(b * Gz + g) * NCHc + blockIdx.x;
  for (int o = t; o < 512; o += 256) {
    const int h = o >> 5, d4c = o & 31;
    *(float4*)&pacc[cb * 2048 + (size_t)h * Dz + d4c * 4] =
        *(const float4*)&Aw[h * 132 + d4c * 4];
  }
  if (t < 16) {
    const int h = t;
    const float m0 = ml[h], m1 = ml[32 + h], m2 = ml[64 + h], m3 = ml[96 + h];
    const float ms = fmaxf(fmaxf(m0, m1), fmaxf(m2, m3));
    const float l = __expf(m0 - ms) * ml[16 + h] + __expf(m1 - ms) * ml[48 + h] +
                    __expf(m2 - ms) * ml[80 + h] + __expf(m3 - ms) * ml[112 + h];
    mbuf[cb * 16 + h] = ms;
    lbuf[cb * 16 + h] = l;
  }
}

// ---------------- combine chunk partials -> ctx (B, H*D)
__global__ __launch_bounds__(512) void attn_combine(
    const float* __restrict__ mbuf, const float* __restrict__ lbuf,
    const float* __restrict__ pacc, const int* __restrict__ positions,
    float* __restrict__ ctx) {
  const int bg = blockIdx.x;
  const int b = bg >> 1, g = bg & 1;
  const int t = threadIdx.x;
  const int h = t >> 5, dg = t & 31;
  const size_t mlb = (size_t)bg * NCHc * 16 + h;
  float mstar = -1e30f;
  for (int c = 0; c < NCHc; c++) mstar = fmaxf(mstar, mbuf[mlb + c * 16]);
  float lsum = 0.f;
  float4 A = make_float4(0.f, 0.f, 0.f, 0.f);
  for (int c = 0; c < NCHc; c++) {
    const float wv = __expf(mbuf[mlb + c * 16] - mstar);
    lsum += wv * lbuf[mlb + c * 16];
    const float4 p = *(const float4*)&pacc[((size_t)bg * NCHc + c) * 2048 + (size_t)h * Dz + dg * 4];
    fma4(A, wv, p);
  }
  const float inv = 1.0f / lsum;
  float4 o = make_float4(A.x * inv, A.y * inv, A.z * inv, A.w * inv);
  *(float4*)&ctx[(size_t)b * (Hz * Dz) + (g * 16 + h) * Dz + dg * 4] = o;
}

// ---------------- reduce dense partials -> out
__global__ __launch_bounds__(256) void reduce_out(
    const float* __restrict__ part, float* __restrict__ out, int KT) {
  const int idx = blockIdx.x * 256 + threadIdx.x;
  const int b = idx >> 12;
  const int j = idx & 4095;
  float s = 0.f;
  for (int kt = 0; kt < KT; kt++) s += part[((size_t)kt * Bz + b) * HIDz + j];
  out[idx] = s;
}

extern "C" void kernel_launch(void* const* d_in, const int* in_sizes, int n_in,
                              void* d_out, int out_size, void* d_ws, size_t ws_size,
                              hipStream_t stream) {
  const float* hidden = (const float*)d_in[0];
  const int* positions = (const int*)d_in[1];
  const float* kcache = (const float*)d_in[2];
  const float* vcache = (const float*)d_in[3];
  const float* Wqkv = (const float*)d_in[4];
  const float* bqkv = (const float*)d_in[5];
  const float* Wd = (const float*)d_in[6];
  float* out = (float*)d_out;

  auto need = [](int KT) -> size_t {
    return (size_t)KT * Bz * QKVz
         + (size_t)Bz * Hz * Dz
         + (size_t)Bz * Gz * Dz * 2
         + (size_t)Bz * Gz * NCHc * 16 * 2
         + (size_t)Bz * Gz * NCHc * 2048
         + (size_t)Bz * HIDz;
  };
  int KT = 32;
  if (need(32) * sizeof(float) > ws_size) KT = 16;
  const int KH = HIDz / KT;

  float* w = (float*)d_ws;
  float* p1 = w;    w += (size_t)KT * Bz * QKVz;
  float* qrot = w;  w += (size_t)Bz * Hz * Dz;
  float* krot = w;  w += (size_t)Bz * Gz * Dz;
  float* vnew = w;  w += (size_t)Bz * Gz * Dz;
  float* mbuf = w;  w += (size_t)Bz * Gz * NCHc * 16;
  float* lbuf = w;  w += (size_t)Bz * Gz * NCHc * 16;
  float* pacc = w;  w += (size_t)Bz * Gz * NCHc * 2048;
  float* ctx = w;

  const size_t smem = (size_t)Bz * (KH + 4) * sizeof(float);

  gemm_partial<<<dim3(QKVz / 128, KT), 256, smem, stream>>>(hidden, Wqkv, p1, HIDz, QKVz, KH);
  qkv_finish<<<dim3(Bz, 9), 256, 0, stream>>>(p1, bqkv, positions, KT, qrot, krot, vnew);
  attn_unit<<<dim3(NCHc, Gz, Bz), 256, 0, stream>>>(qrot, kcache, vcache, krot, vnew, positions,
                                                    mbuf, lbuf, pacc);
  attn_combine<<<dim3(Bz * Gz), 512, 0, stream>>>(mbuf, lbuf, pacc, positions, ctx);
  gemm_partial<<<dim3(HIDz / 128, KT), 256, smem, stream>>>(ctx, Wd, p1, Hz * Dz, HIDz, KH);
  reduce_out<<<dim3(Bz * HIDz / 256), 256, 0, stream>>>(p1, out, KT);
}

// Round 9
// 169.193 us; speedup vs baseline: 1.5191x; 1.0645x over previous
//
#include <hip/hip_runtime.h>
#include <math.h>

#define Bz 32
#define Sz 4096
#define Hz 32
#define Gz 2
#define Dz 128
#define HIDz 4096
#define QKVz 4608
#define NCHc 16   // combine chunks per (b,g) = blocks; block span <= 256 rows

static __device__ __forceinline__ void fma4(float4& a, float s, const float4& v) {
  a.x = fmaf(s, v.x, a.x);
  a.y = fmaf(s, v.y, a.y);
  a.z = fmaf(s, v.z, a.z);
  a.w = fmaf(s, v.w, a.w);
}
static __device__ __forceinline__ float dot4(const float4& a, const float4& b, float acc) {
  return fmaf(a.x, b.x, fmaf(a.y, b.y, fmaf(a.z, b.z, fmaf(a.w, b.w, acc))));
}

// ---------------- split-K GEMM partial: part[kt][b][j] = sum_{k in chunk} X[b][k]*W[k][j]
__global__ __launch_bounds__(256) void gemm_partial(
    const float* __restrict__ X, const float* __restrict__ W,
    float* __restrict__ part, int K, int N, int KH) {
  extern __shared__ float hl[];  // [32][KH+4]
  const int stride = KH + 4;
  const int t = threadIdx.x;
  const int k0 = blockIdx.y * KH;
  const int cols4 = KH >> 2;
  const int total4 = Bz * cols4;
  for (int fi = t; fi < total4; fi += 256) {
    const int row = fi / cols4;
    const int c4 = fi - row * cols4;
    const float4 v = *(const float4*)&X[(size_t)row * K + k0 + c4 * 4];
    *(float4*)&hl[row * stride + c4 * 4] = v;
  }
  __syncthreads();
  const int jl = t & 31;
  const int b0 = (t >> 5) * 4;
  const int j = blockIdx.x * 128 + jl * 4;
  float4 acc[4];
  #pragma unroll
  for (int i = 0; i < 4; i++) acc[i] = make_float4(0.f, 0.f, 0.f, 0.f);
  #pragma unroll 4
  for (int kk = 0; kk < KH; kk += 4) {
    const float4 w0 = *(const float4*)&W[(size_t)(k0 + kk + 0) * N + j];
    const float4 w1 = *(const float4*)&W[(size_t)(k0 + kk + 1) * N + j];
    const float4 w2 = *(const float4*)&W[(size_t)(k0 + kk + 2) * N + j];
    const float4 w3 = *(const float4*)&W[(size_t)(k0 + kk + 3) * N + j];
    #pragma unroll
    for (int bi = 0; bi < 4; bi++) {
      const float4 hb = *(const float4*)&hl[(b0 + bi) * stride + kk];
      fma4(acc[bi], hb.x, w0);
      fma4(acc[bi], hb.y, w1);
      fma4(acc[bi], hb.z, w2);
      fma4(acc[bi], hb.w, w3);
    }
  }
  #pragma unroll
  for (int bi = 0; bi < 4; bi++) {
    *(float4*)&part[((size_t)blockIdx.y * Bz + b0 + bi) * N + j] = acc[bi];
  }
}

// ---------------- reduce QKV partials + bias, RoPE, emit qrot (pre-scaled), krot, vnew
__global__ __launch_bounds__(256) void qkv_finish(
    const float* __restrict__ part, const float* __restrict__ bias,
    const int* __restrict__ positions, int KT,
    float* __restrict__ qrot, float* __restrict__ krot, float* __restrict__ vnew) {
  const int t = threadIdx.x;
  const int b = blockIdx.x;
  const int head = blockIdx.y * 4 + (t >> 6);
  const int tp = t & 63;
  const int j0 = head * Dz + tp * 2;
  float s0 = bias[j0];
  float s1 = bias[j0 + 1];
  for (int kt = 0; kt < KT; kt++) {
    const float2 p = *(const float2*)&part[((size_t)kt * Bz + b) * QKVz + j0];
    s0 += p.x;
    s1 += p.y;
  }
  float o0 = s0, o1 = s1;
  if (head < Hz + Gz && tp < 32) {
    const float invf = exp2f(-(float)tp * (13.287712379549449f / 32.0f));
    const float a = (float)positions[b] * invf;
    float sn, cs;
    sincosf(a, &sn, &cs);
    o0 = s0 * cs - s1 * sn;
    o1 = s1 * cs + s0 * sn;
  }
  if (head < Hz) {
    const float sc = 0.08838834764831845f;
    float2 o = make_float2(o0 * sc, o1 * sc);
    *(float2*)&qrot[((size_t)b * Hz + head) * Dz + tp * 2] = o;
  } else if (head < Hz + Gz) {
    float2 o = make_float2(o0, o1);
    *(float2*)&krot[((size_t)b * Gz + (head - Hz)) * Dz + tp * 2] = o;
  } else {
    float2 o = make_float2(s0, s1);
    *(float2*)&vnew[((size_t)b * Gz + (head - Hz - Gz)) * Dz + tp * 2] = o;
  }
}

// ---------------- flash block: block bx owns contiguous balanced span
// [bx*(pos+1)/16, (bx+1)*(pos+1)/16) (<=256 rows), processed in 32-row K/V tiles staged
// to LDS (coalesced, double-buffered). Wave w computes rows [w*8, w*8+8) of each tile for
// all 16 heads. Lane = (h = lane>>2, dq = lane&3): q[32] in VGPRs; K/V LDS reads are
// 4-address broadcast b128 (conflict-free, no padding). grid (16, G, B), block 256.
__global__ __launch_bounds__(256, 2) void attn_unit(
    const float* __restrict__ qrot, const float* __restrict__ kcache,
    const float* __restrict__ vcache, const float* __restrict__ krot,
    const float* __restrict__ vnew, const int* __restrict__ positions,
    float* __restrict__ mbuf, float* __restrict__ lbuf, float* __restrict__ pacc) {
  __shared__ float kb[2][32 * 128];  // 2 x 16 KB
  __shared__ float vb[2][32 * 128];  // 2 x 16 KB
  __shared__ float ml[128];
  const int g = blockIdx.y, b = blockIdx.z, bx = blockIdx.x;
  const int pos = positions[b];
  const int lt = pos + 1;
  const int blo = (bx * lt) >> 4;
  const int bhi = ((bx + 1) * lt) >> 4;
  const int ntile = (bhi - blo + 31) >> 5;  // block-uniform
  const int t = threadIdx.x;
  const int w = t >> 6, lane = t & 63;
  const int h = lane >> 2, dq = lane & 3;

  // Q in registers (pre-scaled by D^-0.5 in qkv_finish)
  float4 qr[8];
  {
    const float* qsrc = &qrot[((size_t)b * Hz + g * 16 + h) * Dz + dq * 32];
    #pragma unroll
    for (int j = 0; j < 8; ++j) qr[j] = *(const float4*)&qsrc[j * 4];
  }
  const float* krow_new = &krot[((size_t)b * Gz + g) * Dz];
  const float* vrow_new = &vnew[((size_t)b * Gz + g) * Dz];
  const size_t kvb = ((size_t)b * Sz) * (Gz * Dz) + (size_t)g * Dz;

  const int rr0 = t >> 5, c16 = t & 31;  // staging: row, 16B-chunk
  float4 sk[4], sv[4];
#define LOADT(tile)                                                              \
  { _Pragma("unroll") for (int r4 = 0; r4 < 4; ++r4) {                           \
      const int sg = blo + (tile) * 32 + rr0 + r4 * 8;                           \
      const float* kp = (sg >= bhi || sg == pos) ? krow_new                      \
                         : &kcache[kvb + (size_t)sg * (Gz * Dz)];                \
      const float* vp = (sg >= bhi || sg == pos) ? vrow_new                      \
                         : &vcache[kvb + (size_t)sg * (Gz * Dz)];                \
      sk[r4] = *(const float4*)&kp[c16 * 4];                                     \
      sv[r4] = *(const float4*)&vp[c16 * 4]; } }
#define WRITET(buf)                                                              \
  { _Pragma("unroll") for (int r4 = 0; r4 < 4; ++r4) {                           \
      *(float4*)&kb[buf][(rr0 + r4 * 8) * 128 + c16 * 4] = sk[r4];               \
      *(float4*)&vb[buf][(rr0 + r4 * 8) * 128 + c16 * 4] = sv[r4]; } }

  float m_run = -1e30f, l_run = 0.f;
  float4 A[8];
  #pragma unroll
  for (int j = 0; j < 8; ++j) A[j] = make_float4(0.f, 0.f, 0.f, 0.f);

  int cur = 0;
  if (ntile > 0) {
    LOADT(0);
    WRITET(0);
    __syncthreads();
  }
  for (int tile = 0; tile < ntile; ++tile) {
    if (tile + 1 < ntile) LOADT(tile + 1);  // in flight under compute
    const int nvr = bhi - (blo + tile * 32 + w * 8);  // valid rows among this wave's 8
    if (nvr > 0) {
      float lg[8];
      #pragma unroll
      for (int s8 = 0; s8 < 8; ++s8) {
        const float* kRow = &kb[cur][(w * 8 + s8) * 128 + dq * 32];
        float a0 = 0.f, a1 = 0.f, a2 = 0.f, a3 = 0.f;
        #pragma unroll
        for (int jj = 0; jj < 2; ++jj) {
          const float4 k0 = *(const float4*)&kRow[(jj * 4 + 0) * 4];
          const float4 k1 = *(const float4*)&kRow[(jj * 4 + 1) * 4];
          const float4 k2 = *(const float4*)&kRow[(jj * 4 + 2) * 4];
          const float4 k3 = *(const float4*)&kRow[(jj * 4 + 3) * 4];
          a0 = dot4(qr[jj * 4 + 0], k0, a0);
          a1 = dot4(qr[jj * 4 + 1], k1, a1);
          a2 = dot4(qr[jj * 4 + 2], k2, a2);
          a3 = dot4(qr[jj * 4 + 3], k3, a3);
        }
        float acc = (a0 + a1) + (a2 + a3);
        acc += __shfl_xor(acc, 1);
        acc += __shfl_xor(acc, 2);
        lg[s8] = acc;  // full 128-d logit in all 4 dq lanes
      }
      float tm = -1e30f;
      #pragma unroll
      for (int s8 = 0; s8 < 8; ++s8) tm = fmaxf(tm, (s8 < nvr) ? lg[s8] : -1e30f);
      const float mn = fmaxf(m_run, tm);
      const float sc = __expf(m_run - mn);
      m_run = mn;
      l_run *= sc;
      #pragma unroll
      for (int j = 0; j < 8; ++j) {
        A[j].x *= sc; A[j].y *= sc; A[j].z *= sc; A[j].w *= sc;
      }
      float ps = 0.f;
      #pragma unroll
      for (int s8 = 0; s8 < 8; ++s8) {
        const float p = (s8 < nvr) ? __expf(lg[s8] - mn) : 0.f;
        lg[s8] = p;
        ps += p;
      }
      l_run += ps;
      #pragma unroll
      for (int s8 = 0; s8 < 8; ++s8) {
        const float* vRow = &vb[cur][(w * 8 + s8) * 128 + dq * 32];
        const float p = lg[s8];
        #pragma unroll
        for (int j = 0; j < 8; ++j) {
          const float4 vv = *(const float4*)&vRow[j * 4];
          fma4(A[j], p, vv);
        }
      }
    }
    if (tile + 1 < ntile) {
      WRITET(cur ^ 1);       // fills the idle buffer; safe during others' compute
      __syncthreads();
      cur ^= 1;
    }
  }

  // ---- in-block combine of 4 wave partials (serial through Aw = kb[0])
  __syncthreads();  // all compute done before aliasing kb
  if (dq == 0) {
    ml[w * 32 + h] = m_run;
    ml[w * 32 + 16 + h] = l_run;
  }
  __syncthreads();
  const float ms = fmaxf(fmaxf(ml[h], ml[32 + h]), fmaxf(ml[64 + h], ml[96 + h]));
  const float ew = __expf(m_run - ms);
  float* Aw = kb[0];  // 16 x 132 layout
  for (int step = 0; step < 4; ++step) {
    if (w == step) {
      #pragma unroll
      for (int j = 0; j < 8; ++j) {
        float4 x;
        if (step == 0) {
          x = make_float4(ew * A[j].x, ew * A[j].y, ew * A[j].z, ew * A[j].w);
        } else {
          x = *(const float4*)&Aw[h * 132 + dq * 32 + j * 4];
          fma4(x, ew, A[j]);
        }
        *(float4*)&Aw[h * 132 + dq * 32 + j * 4] = x;
      }
    }
    __syncthreads();
  }
  const size_t cb = (size_t)(b * Gz + g) * NCHc + bx;
  for (int o = t; o < 512; o += 256) {
    const int hh = o >> 5, d4c = o & 31;
    *(float4*)&pacc[cb * 2048 + (size_t)hh * Dz + d4c * 4] =
        *(const float4*)&Aw[hh * 132 + d4c * 4];
  }
  if (t < 16) {
    const int hh = t;
    const float m0 = ml[hh], m1 = ml[32 + hh], m2 = ml[64 + hh], m3 = ml[96 + hh];
    const float msf = fmaxf(fmaxf(m0, m1), fmaxf(m2, m3));
    const float l = __expf(m0 - msf) * ml[16 + hh] + __expf(m1 - msf) * ml[48 + hh] +
                    __expf(m2 - msf) * ml[80 + hh] + __expf(m3 - msf) * ml[112 + hh];
    mbuf[cb * 16 + hh] = msf;
    lbuf[cb * 16 + hh] = l;
  }
#undef LOADT
#undef WRITET
}

// ---------------- combine chunk partials -> ctx (B, H*D)
__global__ __launch_bounds__(512) void attn_combine(
    const float* __restrict__ mbuf, const float* __restrict__ lbuf,
    const float* __restrict__ pacc, const int* __restrict__ positions,
    float* __restrict__ ctx) {
  const int bg = blockIdx.x;
  const int b = bg >> 1, g = bg & 1;
  const int t = threadIdx.x;
  const int h = t >> 5, dg = t & 31;
  const size_t mlb = (size_t)bg * NCHc * 16 + h;
  float mstar = -1e30f;
  for (int c = 0; c < NCHc; c++) mstar = fmaxf(mstar, mbuf[mlb + c * 16]);
  float lsum = 0.f;
  float4 A = make_float4(0.f, 0.f, 0.f, 0.f);
  for (int c = 0; c < NCHc; c++) {
    const float wv = __expf(mbuf[mlb + c * 16] - mstar);
    lsum += wv * lbuf[mlb + c * 16];
    const float4 p = *(const float4*)&pacc[((size_t)bg * NCHc + c) * 2048 + (size_t)h * Dz + dg * 4];
    fma4(A, wv, p);
  }
  const float inv = 1.0f / lsum;
  float4 o = make_float4(A.x * inv, A.y * inv, A.z * inv, A.w * inv);
  *(float4*)&ctx[(size_t)b * (Hz * Dz) + (g * 16 + h) * Dz + dg * 4] = o;
}

// ---------------- reduce dense partials -> out
__global__ __launch_bounds__(256) void reduce_out(
    const float* __restrict__ part, float* __restrict__ out, int KT) {
  const int idx = blockIdx.x * 256 + threadIdx.x;
  const int b = idx >> 12;
  const int j = idx & 4095;
  float s = 0.f;
  for (int kt = 0; kt < KT; kt++) s += part[((size_t)kt * Bz + b) * HIDz + j];
  out[idx] = s;
}

extern "C" void kernel_launch(void* const* d_in, const int* in_sizes, int n_in,
                              void* d_out, int out_size, void* d_ws, size_t ws_size,
                              hipStream_t stream) {
  const float* hidden = (const float*)d_in[0];
  const int* positions = (const int*)d_in[1];
  const float* kcache = (const float*)d_in[2];
  const float* vcache = (const float*)d_in[3];
  const float* Wqkv = (const float*)d_in[4];
  const float* bqkv = (const float*)d_in[5];
  const float* Wd = (const float*)d_in[6];
  float* out = (float*)d_out;

  auto need = [](int KT) -> size_t {
    return (size_t)KT * Bz * QKVz
         + (size_t)Bz * Hz * Dz
         + (size_t)Bz * Gz * Dz * 2
         + (size_t)Bz * Gz * NCHc * 16 * 2
         + (size_t)Bz * Gz * NCHc * 2048
         + (size_t)Bz * HIDz;
  };
  int KT = 32;
  if (need(32) * sizeof(float) > ws_size) KT = 16;
  const int KH = HIDz / KT;

  float* w = (float*)d_ws;
  float* p1 = w;    w += (size_t)KT * Bz * QKVz;
  float* qrot = w;  w += (size_t)Bz * Hz * Dz;
  float* krot = w;  w += (size_t)Bz * Gz * Dz;
  float* vnew = w;  w += (size_t)Bz * Gz * Dz;
  float* mbuf = w;  w += (size_t)Bz * Gz * NCHc * 16;
  float* lbuf = w;  w += (size_t)Bz * Gz * NCHc * 16;
  float* pacc = w;  w += (size_t)Bz * Gz * NCHc * 2048;
  float* ctx = w;

  const size_t smem = (size_t)Bz * (KH + 4) * sizeof(float);

  gemm_partial<<<dim3(QKVz / 128, KT), 256, smem, stream>>>(hidden, Wqkv, p1, HIDz, QKVz, KH);
  qkv_finish<<<dim3(Bz, 9), 256, 0, stream>>>(p1, bqkv, positions, KT, qrot, krot, vnew);
  attn_unit<<<dim3(NCHc, Gz, Bz), 256, 0, stream>>>(qrot, kcache, vcache, krot, vnew, positions,
                                                    mbuf, lbuf, pacc);
  attn_combine<<<dim3(Bz * Gz), 512, 0, stream>>>(mbuf, lbuf, pacc, positions, ctx);
  gemm_partial<<<dim3(HIDz / 128, KT), 256, smem, stream>>>(ctx, Wd, p1, Hz * Dz, HIDz, KH);
  reduce_out<<<dim3(Bz * HIDz / 256), 256, 0, stream>>>(p1, out, KT);
}